// Round 1
// baseline (200.601 us; speedup 1.0000x reference)
//
#include <hip/hip_runtime.h>
#include <math.h>

// PNA layer, restructured:
//   u = h@W1, v = h@W2 + b_pre           (W_pre rows [0:64) and [64:128))
//   e[n,d] = relu(u[nbr[n,d]] + v[n] + ea[n,d]@W3)   (W3 = W_pre rows [128:144))
//   agg = [mean,max,min,std] over d      -> 256 per node
//   scalers fold into W_eff[256][64] = Wp1[64:320] + c1*Wp1[320:576] + c2*Wp1[576:832]
//   y1 = relu(h@Wp1[0:64] + agg@W_eff + b_post1)
//   out = y1@W_post2 + b_post2 + h

#define N_NODES 65536
#define D_NBR 16
#define F_DIM 64
#define FE_DIM 16

// ---------------- K1: per-node linear terms ----------------
// 16 nodes per block; W12 (128x64) staged in LDS.
__global__ __launch_bounds__(256) void k_uv(const float* __restrict__ h,
                                            const float* __restrict__ W_pre,
                                            const float* __restrict__ b_pre,
                                            float* __restrict__ u,
                                            float* v /* aliased with d_out */) {
    __shared__ float W12[128 * 64];   // 32 KB
    __shared__ float hl[16 * 64];     // 4 KB
    int t = threadIdx.x;
    for (int i = t; i < 128 * 64; i += 256) W12[i] = W_pre[i];
    int base = blockIdx.x * 16 * 64;  // 16 nodes * 64 feats
    for (int i = t; i < 16 * 64; i += 256) hl[i] = h[base + i];
    __syncthreads();
    int f = t & 63;
    int r0 = t >> 6;                  // 0..3
    float bp = b_pre[f];
    #pragma unroll
    for (int c = 0; c < 4; ++c) {
        int r = r0 + 4 * c;           // local node 0..15
        float au = 0.f, av = 0.f;
        #pragma unroll 16
        for (int k = 0; k < 64; ++k) {
            float hv = hl[r * 64 + k];
            au = fmaf(hv, W12[k * 64 + f], au);
            av = fmaf(hv, W12[(64 + k) * 64 + f], av);
        }
        u[base + r * 64 + f] = au;
        v[base + r * 64 + f] = av + bp;
    }
}

// ---------------- K2: fold degree scalers into W_eff ----------------
__global__ __launch_bounds__(256) void k_weff(const float* __restrict__ Wp1,
                                              float* __restrict__ Weff,
                                              float c1, float c2) {
    int i = blockIdx.x * 256 + threadIdx.x;   // 0..16383
    Weff[i] = Wp1[4096 + i] + c1 * Wp1[20480 + i] + c2 * Wp1[36864 + i];
}

// ---------------- K3: fused pretrans+aggregate+posttrans ----------------
// 4 nodes per block, 64 threads per node (thread = output feature f).
__global__ __launch_bounds__(256) void k_main(
    const float* __restrict__ h,
    const float* __restrict__ edge_attr,
    const int* __restrict__ nbr_idx,
    const float* __restrict__ W_pre,
    const float* __restrict__ W_post1,
    const float* __restrict__ b_post1,
    const float* __restrict__ W_post2,
    const float* __restrict__ b_post2,
    const float* __restrict__ u,
    const float* vbuf,            // aliased with out (read-before-write, same rows)
    const float* __restrict__ Weff,
    float* out) {
    __shared__ float W3l[16 * 64];    // 4 KB
    __shared__ float eal[4][256];     // 4 KB   [node][d*16+i]
    __shared__ float hl[4][64];       // 1 KB
    __shared__ float aggl[4][256];    // 4 KB
    __shared__ float part[4][4][64];  // 4 KB   [group][node][f]
    __shared__ float y1l[4][64];      // 1 KB
    __shared__ int   nb[4][16];

    int t = threadIdx.x;
    int nb_base = blockIdx.x * 4;     // first node of the block

    for (int i = t; i < 16 * 64; i += 256) W3l[i] = W_pre[128 * 64 + i];
    {   // 4 nodes * D*FE = 1024 floats, as float4
        const float4* src = (const float4*)(edge_attr + (size_t)nb_base * 256);
        ((float4*)&eal[0][0])[t] = src[t];
    }
    ((float*)hl)[t] = h[nb_base * 64 + t];
    if (t < 64) ((int*)nb)[t] = nbr_idx[nb_base * 16 + t];
    __syncthreads();

    int nn = t >> 6, f = t & 63;
    int n = nb_base + nn;

    // ---- pretrans + aggregation for node nn, feature f ----
    float w3c[16];
    #pragma unroll
    for (int i = 0; i < 16; ++i) w3c[i] = W3l[i * 64 + f];
    float vv = vbuf[(size_t)n * 64 + f];

    float s1 = 0.f, s2 = 0.f, mx = -1e30f, mn = 1e30f;
    #pragma unroll 4
    for (int d = 0; d < D_NBR; ++d) {
        int j = nb[nn][d];
        float e = u[(size_t)j * 64 + f] + vv;
        #pragma unroll
        for (int i = 0; i < 16; ++i)
            e = fmaf(eal[nn][d * 16 + i], w3c[i], e);
        e = fmaxf(e, 0.f);
        s1 += e;
        s2 = fmaf(e, e, s2);
        mx = fmaxf(mx, e);
        mn = fminf(mn, e);
    }
    float mean = s1 * 0.0625f;
    float var  = fmaxf(fmaf(-mean, mean, s2 * 0.0625f), 0.f);
    float sd   = sqrtf(var + 1e-5f);
    aggl[nn][f]       = mean;
    aggl[nn][64 + f]  = mx;
    aggl[nn][128 + f] = mn;
    aggl[nn][192 + f] = sd;
    __syncthreads();

    // ---- posttrans layer 1: k-split across the 4 thread-groups, 4-node amortized ----
    int g = nn;
    float p0 = 0.f, p1 = 0.f, p2 = 0.f, p3 = 0.f;
    #pragma unroll
    for (int k0 = 0; k0 < 16; ++k0) {           // h part: k = g*16 .. g*16+15
        int k = g * 16 + k0;
        float w = W_post1[k * 64 + f];
        p0 = fmaf(hl[0][k], w, p0);
        p1 = fmaf(hl[1][k], w, p1);
        p2 = fmaf(hl[2][k], w, p2);
        p3 = fmaf(hl[3][k], w, p3);
    }
    #pragma unroll 8
    for (int k0 = 0; k0 < 64; ++k0) {           // agg part: k = g*64 .. g*64+63
        int k = g * 64 + k0;
        float w = Weff[k * 64 + f];
        p0 = fmaf(aggl[0][k], w, p0);
        p1 = fmaf(aggl[1][k], w, p1);
        p2 = fmaf(aggl[2][k], w, p2);
        p3 = fmaf(aggl[3][k], w, p3);
    }
    part[g][0][f] = p0;
    part[g][1][f] = p1;
    part[g][2][f] = p2;
    part[g][3][f] = p3;
    __syncthreads();

    float y = b_post1[f] + part[0][g][f] + part[1][g][f] + part[2][g][f] + part[3][g][f];
    y1l[g][f] = fmaxf(y, 0.f);
    __syncthreads();

    // ---- posttrans layer 2 + residual ----
    float o = b_post2[f];
    #pragma unroll 8
    for (int k = 0; k < 64; ++k)
        o = fmaf(y1l[g][k], W_post2[k * 64 + f], o);
    out[(size_t)n * 64 + f] = o + hl[g][f];
}

extern "C" void kernel_launch(void* const* d_in, const int* in_sizes, int n_in,
                              void* d_out, int out_size, void* d_ws, size_t ws_size,
                              hipStream_t stream) {
    const float* h         = (const float*)d_in[0];
    const float* edge_attr = (const float*)d_in[1];
    const int*   nbr_idx   = (const int*)d_in[2];
    const float* W_pre     = (const float*)d_in[3];
    const float* b_pre     = (const float*)d_in[4];
    const float* W_post1   = (const float*)d_in[5];
    const float* b_post1   = (const float*)d_in[6];
    const float* W_post2   = (const float*)d_in[7];
    const float* b_post2   = (const float*)d_in[8];
    float* out = (float*)d_out;

    size_t need = ((size_t)N_NODES * 64 + 256 * 64) * sizeof(float);
    if (ws_size < need) return;   // workspace assumption: ~16.1 MiB
    float* u    = (float*)d_ws;                    // [N,64]
    float* weff = u + (size_t)N_NODES * 64;        // [256,64]

    double logD = log((double)D_NBR + 1.0);        // log(17)
    const double AVG = 2.302585092994046;
    float c1 = (float)(logD / AVG);
    float c2 = (float)(AVG / logD);

    // v (= h@W2 + b_pre) lives temporarily in d_out; k_main reads each row
    // before overwriting it (same block, read phase precedes final store).
    k_uv<<<N_NODES / 16, 256, 0, stream>>>(h, W_pre, b_pre, u, out);
    k_weff<<<64, 256, 0, stream>>>(W_post1, weff, c1, c2);
    k_main<<<N_NODES / 4, 256, 0, stream>>>(h, edge_attr, nbr_idx, W_pre,
                                            W_post1, b_post1, W_post2, b_post2,
                                            u, out, weff, out);
}

// Round 2
// 136.072 us; speedup vs baseline: 1.4742x; 1.4742x over previous
//
#include <hip/hip_runtime.h>
#include <math.h>

// PNA layer, restructured (R2: float4 register-blocked, LDS-b128 everywhere):
//   u = h@W1, v = h@W2 + b_pre           (W_pre rows [0:64) and [64:128))
//   e[n,d] = relu(u[nbr[n,d]] + v[n] + ea[n,d]@W3 )  (W3 = W_pre rows [128:144))
//   agg = [mean,max,min,std] over d
//   scalers fold: W_eff[256][64] = Wp1[64:320] + c1*Wp1[320:576] + c2*Wp1[576:832]
//   y1 = relu(h@Wp1[0:64] + agg@W_eff + b_post1);  out = y1@W_post2 + b_post2 + h

#define N_NODES 65536
#define D_NBR 16

// ---------------- K1: u = h@W1, v = h@W2 + b_pre ----------------
// 16 nodes/block, thread = (node r, 4 features f4). All LDS reads are b128.
__global__ __launch_bounds__(256) void k_uv(const float* __restrict__ h,
                                            const float* __restrict__ W_pre,
                                            const float* __restrict__ b_pre,
                                            float* __restrict__ u,
                                            float* v /* aliased with d_out */) {
    __shared__ float W12[128 * 64];   // 32 KB
    __shared__ float hl[16 * 64];     // 4 KB
    int t = threadIdx.x;
    {
        const float4* wsrc = (const float4*)W_pre;
        float4* wdst = (float4*)W12;
        #pragma unroll
        for (int q = 0; q < 8; ++q) wdst[q * 256 + t] = wsrc[q * 256 + t];
    }
    int base = blockIdx.x * 16 * 64;
    ((float4*)hl)[t] = ((const float4*)(h + base))[t];
    __syncthreads();

    int r = t >> 4, f4 = (t & 15) * 4;
    float au0 = 0.f, au1 = 0.f, au2 = 0.f, au3 = 0.f;
    float av0 = 0.f, av1 = 0.f, av2 = 0.f, av3 = 0.f;
    #pragma unroll
    for (int k = 0; k < 64; k += 4) {
        float4 hv = *(const float4*)&hl[r * 64 + k];
        float hk;
        #define UV_STEP(KK, HK)                                              \
        {   hk = HK;                                                         \
            float4 wu = *(const float4*)&W12[(k + KK) * 64 + f4];            \
            float4 wv = *(const float4*)&W12[(64 + k + KK) * 64 + f4];       \
            au0 = fmaf(hk, wu.x, au0); au1 = fmaf(hk, wu.y, au1);            \
            au2 = fmaf(hk, wu.z, au2); au3 = fmaf(hk, wu.w, au3);            \
            av0 = fmaf(hk, wv.x, av0); av1 = fmaf(hk, wv.y, av1);            \
            av2 = fmaf(hk, wv.z, av2); av3 = fmaf(hk, wv.w, av3); }
        UV_STEP(0, hv.x) UV_STEP(1, hv.y) UV_STEP(2, hv.z) UV_STEP(3, hv.w)
        #undef UV_STEP
    }
    float4 bp = *(const float4*)&b_pre[f4];
    float4 uo; uo.x = au0; uo.y = au1; uo.z = au2; uo.w = au3;
    float4 vo; vo.x = av0 + bp.x; vo.y = av1 + bp.y; vo.z = av2 + bp.z; vo.w = av3 + bp.w;
    *(float4*)&u[base + r * 64 + f4] = uo;
    *(float4*)&v[base + r * 64 + f4] = vo;
}

// ---------------- K2: fold degree scalers into W_eff ----------------
__global__ __launch_bounds__(256) void k_weff(const float* __restrict__ Wp1,
                                              float* __restrict__ Weff,
                                              float c1, float c2) {
    int i = blockIdx.x * 256 + threadIdx.x;   // 0..16383
    Weff[i] = Wp1[4096 + i] + c1 * Wp1[20480 + i] + c2 * Wp1[36864 + i];
}

// ---------------- K3: fused pretrans + aggregate + posttrans ----------------
// 16 nodes/block, 256 threads.
// Phase A (pretrans): thread = (node nn = t>>4, features f4 = (t&15)*4).
// Phase B (post MLP): thread = (k-group g = t>>6, feature f = t&63), 16-node reg-block.
__global__ __launch_bounds__(256) void k_main(
    const float* __restrict__ h,
    const float* __restrict__ edge_attr,
    const int* __restrict__ nbr_idx,
    const float* __restrict__ W_pre,
    const float* __restrict__ W_post1,
    const float* __restrict__ b_post1,
    const float* __restrict__ W_post2,
    const float* __restrict__ b_post2,
    const float* __restrict__ u,
    const float* vbuf,            // aliased with out (read-before-write, same rows)
    const float* __restrict__ Weff,
    float* out) {
    __shared__ float hl[16 * 64];     // 4 KB
    __shared__ float aggl[16 * 260];  // 16.25 KB (padded rows: +4 banks/row)
    __shared__ float w3l[16 * 64];    // 4 KB
    __shared__ int   nbl[256];        // 1 KB
    __shared__ float scratch[5120];   // 20 KB: phase A = eal[16][260]; phase B = part[4][16][64] + y1l[16][64]

    int t = threadIdx.x;
    int blk = blockIdx.x * 16;        // first node of block

    // ---- phase A loads ----
    {
        const float4* easrc = (const float4*)(edge_attr + (size_t)blk * 256);
        #pragma unroll
        for (int q = 0; q < 4; ++q) {
            int j = q * 256 + t;               // 0..1023 (float4 index)
            int node = j >> 6, p4 = j & 63;    // 64 float4 per node row
            *((float4*)&scratch[node * 260] + p4) = easrc[j];
        }
        ((float4*)hl)[t] = ((const float4*)(h + (size_t)blk * 64))[t];
        ((float4*)w3l)[t] = ((const float4*)(W_pre + 128 * 64))[t];
        nbl[t] = nbr_idx[blk * 16 + t];
    }
    __syncthreads();

    // ---- pretrans + aggregation ----
    {
        int nn = t >> 4, f4 = (t & 15) * 4;
        int n = blk + nn;
        float4 w3c[16];
        #pragma unroll
        for (int i = 0; i < 16; ++i) w3c[i] = *(const float4*)&w3l[i * 64 + f4];
        float4 vv = *(const float4*)&vbuf[(size_t)n * 64 + f4];

        float s10 = 0.f, s11 = 0.f, s12 = 0.f, s13 = 0.f;
        float s20 = 0.f, s21 = 0.f, s22 = 0.f, s23 = 0.f;
        float mx0 = -1e30f, mx1 = -1e30f, mx2 = -1e30f, mx3 = -1e30f;
        float mn0 = 1e30f, mn1 = 1e30f, mn2 = 1e30f, mn3 = 1e30f;
        const float* earow = &scratch[nn * 260];

        #pragma unroll
        for (int d = 0; d < D_NBR; ++d) {
            int j = nbl[nn * 16 + d];
            float4 uu = *(const float4*)&u[(size_t)j * 64 + f4];
            float e0 = uu.x + vv.x, e1 = uu.y + vv.y, e2 = uu.z + vv.z, e3 = uu.w + vv.w;
            #pragma unroll
            for (int i = 0; i < 16; i += 4) {
                float4 ea = *(const float4*)&earow[d * 16 + i];
                e0 = fmaf(ea.x, w3c[i].x, e0);     e1 = fmaf(ea.x, w3c[i].y, e1);
                e2 = fmaf(ea.x, w3c[i].z, e2);     e3 = fmaf(ea.x, w3c[i].w, e3);
                e0 = fmaf(ea.y, w3c[i + 1].x, e0); e1 = fmaf(ea.y, w3c[i + 1].y, e1);
                e2 = fmaf(ea.y, w3c[i + 1].z, e2); e3 = fmaf(ea.y, w3c[i + 1].w, e3);
                e0 = fmaf(ea.z, w3c[i + 2].x, e0); e1 = fmaf(ea.z, w3c[i + 2].y, e1);
                e2 = fmaf(ea.z, w3c[i + 2].z, e2); e3 = fmaf(ea.z, w3c[i + 2].w, e3);
                e0 = fmaf(ea.w, w3c[i + 3].x, e0); e1 = fmaf(ea.w, w3c[i + 3].y, e1);
                e2 = fmaf(ea.w, w3c[i + 3].z, e2); e3 = fmaf(ea.w, w3c[i + 3].w, e3);
            }
            e0 = fmaxf(e0, 0.f); e1 = fmaxf(e1, 0.f); e2 = fmaxf(e2, 0.f); e3 = fmaxf(e3, 0.f);
            s10 += e0; s11 += e1; s12 += e2; s13 += e3;
            s20 = fmaf(e0, e0, s20); s21 = fmaf(e1, e1, s21);
            s22 = fmaf(e2, e2, s22); s23 = fmaf(e3, e3, s23);
            mx0 = fmaxf(mx0, e0); mx1 = fmaxf(mx1, e1); mx2 = fmaxf(mx2, e2); mx3 = fmaxf(mx3, e3);
            mn0 = fminf(mn0, e0); mn1 = fminf(mn1, e1); mn2 = fminf(mn2, e2); mn3 = fminf(mn3, e3);
        }
        float m0 = s10 * 0.0625f, m1 = s11 * 0.0625f, m2 = s12 * 0.0625f, m3 = s13 * 0.0625f;
        float4 mean4; mean4.x = m0; mean4.y = m1; mean4.z = m2; mean4.w = m3;
        float4 max4;  max4.x = mx0; max4.y = mx1; max4.z = mx2; max4.w = mx3;
        float4 min4;  min4.x = mn0; min4.y = mn1; min4.z = mn2; min4.w = mn3;
        float4 sd4;
        sd4.x = sqrtf(fmaxf(fmaf(-m0, m0, s20 * 0.0625f), 0.f) + 1e-5f);
        sd4.y = sqrtf(fmaxf(fmaf(-m1, m1, s21 * 0.0625f), 0.f) + 1e-5f);
        sd4.z = sqrtf(fmaxf(fmaf(-m2, m2, s22 * 0.0625f), 0.f) + 1e-5f);
        sd4.w = sqrtf(fmaxf(fmaf(-m3, m3, s23 * 0.0625f), 0.f) + 1e-5f);
        float* arow = &aggl[nn * 260];
        *(float4*)&arow[f4]       = mean4;
        *(float4*)&arow[64 + f4]  = max4;
        *(float4*)&arow[128 + f4] = min4;
        *(float4*)&arow[192 + f4] = sd4;
    }
    __syncthreads();   // also fences all eal (scratch) reads before part writes

    // ---- posttrans layer 1: k-split over 4 groups, 16-node register block ----
    int f = t & 63, g = t >> 6;
    {
        float p[16];
        #pragma unroll
        for (int node = 0; node < 16; ++node) p[node] = 0.f;

        // h part: rows g*16 .. g*16+15 of W_post1
        #pragma unroll
        for (int c = 0; c < 4; ++c) {
            int k = g * 16 + c * 4;
            float w0 = W_post1[(k + 0) * 64 + f];
            float w1 = W_post1[(k + 1) * 64 + f];
            float w2 = W_post1[(k + 2) * 64 + f];
            float w3 = W_post1[(k + 3) * 64 + f];
            #pragma unroll
            for (int node = 0; node < 16; ++node) {
                float4 hv = *(const float4*)&hl[node * 64 + k];
                p[node] = fmaf(hv.x, w0, fmaf(hv.y, w1, fmaf(hv.z, w2, fmaf(hv.w, w3, p[node]))));
            }
        }
        // agg part: rows g*64 .. g*64+63 of Weff
        for (int c = 0; c < 16; ++c) {
            int k = g * 64 + c * 4;
            float w0 = Weff[(k + 0) * 64 + f];
            float w1 = Weff[(k + 1) * 64 + f];
            float w2 = Weff[(k + 2) * 64 + f];
            float w3 = Weff[(k + 3) * 64 + f];
            #pragma unroll
            for (int node = 0; node < 16; ++node) {
                float4 av = *(const float4*)&aggl[node * 260 + k];
                p[node] = fmaf(av.x, w0, fmaf(av.y, w1, fmaf(av.z, w2, fmaf(av.w, w3, p[node]))));
            }
        }
        float* part = scratch;   // part[g][node][f]
        #pragma unroll
        for (int node = 0; node < 16; ++node) part[(g * 16 + node) * 64 + f] = p[node];
    }
    __syncthreads();

    // ---- y1 = relu(bias + sum of 4 partials) ----
    {
        const float* part = scratch;
        float* y1l = scratch + 4096;
        float bp = b_post1[f];
        #pragma unroll
        for (int q = 0; q < 4; ++q) {
            int node = g * 4 + q;
            float y = bp + part[(0 * 16 + node) * 64 + f] + part[(1 * 16 + node) * 64 + f]
                         + part[(2 * 16 + node) * 64 + f] + part[(3 * 16 + node) * 64 + f];
            y1l[node * 64 + f] = fmaxf(y, 0.f);
        }
    }
    __syncthreads();

    // ---- posttrans layer 2 + residual: thread handles nodes g*4..g*4+3 ----
    {
        const float* y1l = scratch + 4096;
        float bp2 = b_post2[f];
        float a0 = bp2, a1 = bp2, a2 = bp2, a3 = bp2;
        for (int c = 0; c < 16; ++c) {
            int k = c * 4;
            float w0 = W_post2[(k + 0) * 64 + f];
            float w1 = W_post2[(k + 1) * 64 + f];
            float w2 = W_post2[(k + 2) * 64 + f];
            float w3 = W_post2[(k + 3) * 64 + f];
            float4 y0 = *(const float4*)&y1l[(g * 4 + 0) * 64 + k];
            float4 y1v = *(const float4*)&y1l[(g * 4 + 1) * 64 + k];
            float4 y2 = *(const float4*)&y1l[(g * 4 + 2) * 64 + k];
            float4 y3 = *(const float4*)&y1l[(g * 4 + 3) * 64 + k];
            a0 = fmaf(y0.x, w0, fmaf(y0.y, w1, fmaf(y0.z, w2, fmaf(y0.w, w3, a0))));
            a1 = fmaf(y1v.x, w0, fmaf(y1v.y, w1, fmaf(y1v.z, w2, fmaf(y1v.w, w3, a1))));
            a2 = fmaf(y2.x, w0, fmaf(y2.y, w1, fmaf(y2.z, w2, fmaf(y2.w, w3, a2))));
            a3 = fmaf(y3.x, w0, fmaf(y3.y, w1, fmaf(y3.z, w2, fmaf(y3.w, w3, a3))));
        }
        out[(size_t)(blk + g * 4 + 0) * 64 + f] = a0 + hl[(g * 4 + 0) * 64 + f];
        out[(size_t)(blk + g * 4 + 1) * 64 + f] = a1 + hl[(g * 4 + 1) * 64 + f];
        out[(size_t)(blk + g * 4 + 2) * 64 + f] = a2 + hl[(g * 4 + 2) * 64 + f];
        out[(size_t)(blk + g * 4 + 3) * 64 + f] = a3 + hl[(g * 4 + 3) * 64 + f];
    }
}

extern "C" void kernel_launch(void* const* d_in, const int* in_sizes, int n_in,
                              void* d_out, int out_size, void* d_ws, size_t ws_size,
                              hipStream_t stream) {
    const float* h         = (const float*)d_in[0];
    const float* edge_attr = (const float*)d_in[1];
    const int*   nbr_idx   = (const int*)d_in[2];
    const float* W_pre     = (const float*)d_in[3];
    const float* b_pre     = (const float*)d_in[4];
    const float* W_post1   = (const float*)d_in[5];
    const float* b_post1   = (const float*)d_in[6];
    const float* W_post2   = (const float*)d_in[7];
    const float* b_post2   = (const float*)d_in[8];
    float* out = (float*)d_out;

    size_t need = ((size_t)N_NODES * 64 + 256 * 64) * sizeof(float);
    if (ws_size < need) return;
    float* u    = (float*)d_ws;                    // [N,64]
    float* weff = u + (size_t)N_NODES * 64;        // [256,64]

    double logD = log((double)D_NBR + 1.0);        // log(17)
    const double AVG = 2.302585092994046;
    float c1 = (float)(logD / AVG);
    float c2 = (float)(AVG / logD);

    k_uv<<<N_NODES / 16, 256, 0, stream>>>(h, W_pre, b_pre, u, out);
    k_weff<<<64, 256, 0, stream>>>(W_post1, weff, c1, c2);
    k_main<<<N_NODES / 16, 256, 0, stream>>>(h, edge_attr, nbr_idx, W_pre,
                                             W_post1, b_post1, W_post2, b_post2,
                                             u, out, weff, out);
}

// Round 3
// 97.290 us; speedup vs baseline: 2.0619x; 1.3986x over previous
//
#include <hip/hip_runtime.h>
#include <math.h>

// PNA layer, R3: bf16 MFMA everywhere.
//   u = h@W1 + b_pre  (bf16, precomputed)          W1 = W_pre rows 0:64
//   per 16-node group:
//     v = h@W2 (MFMA, regs)                        W2 = W_pre rows 64:128
//     e = relu( mfma(ea, W3, Cinit=u[nbr]+v) )     W3 = W_pre rows 128:144
//     agg = [mean,max,min,std] over d (shfl butterfly on C-frag rows)
//     y1 = relu( [h,agg] @ Wfull + b_post1 )       Wfull = scaler-folded [320][64]
//     out = y1 @ W_post2 + b_post2 + h
// MFMA 16x16x32_bf16 layouts (m89-verified):
//   A: row = lane&15, k = (lane>>4)*8 + j   (8 bf16 / lane, b128 from LDS)
//   B: col = lane&15, k = (lane>>4)*8 + j   (weights stored transposed [col][k])
//   C/D: col = lane&15, row = (lane>>4)*4 + reg

#define N_NODES 65536
#define NGROUPS 4096
#define GRID_MAIN 1024

typedef float f32x4 __attribute__((ext_vector_type(4)));
typedef short s16x8 __attribute__((ext_vector_type(8)));
typedef unsigned short us4 __attribute__((ext_vector_type(4)));

__device__ __forceinline__ unsigned short f2bf(float f) {
    union { float f; unsigned int u; } v; v.f = f;
    unsigned int r = v.u + 0x7fffu + ((v.u >> 16) & 1u);   // RNE
    return (unsigned short)(r >> 16);
}
__device__ __forceinline__ float bf2f(unsigned short u) {
    union { unsigned int u; float f; } v; v.u = ((unsigned int)u) << 16; return v.f;
}

// ---------------- prep: transposed bf16 weights ----------------
__global__ __launch_bounds__(256) void k_w(const float* __restrict__ Wpre,
                                           const float* __restrict__ Wp1,
                                           const float* __restrict__ Wp2,
                                           unsigned short* __restrict__ wfullT,
                                           unsigned short* __restrict__ w2T,
                                           unsigned short* __restrict__ w3T,
                                           unsigned short* __restrict__ wp2T,
                                           float c1, float c2) {
    int c = blockIdx.x;            // output col 0..63
    int t = threadIdx.x;
    for (int k = t; k < 320; k += 256) {
        float v;
        if (k < 64) v = Wp1[k * 64 + c];
        else {
            int kk = k - 64;
            v = Wp1[(64 + kk) * 64 + c] + c1 * Wp1[(320 + kk) * 64 + c]
                                        + c2 * Wp1[(576 + kk) * 64 + c];
        }
        wfullT[c * 320 + k] = f2bf(v);
    }
    if (t < 64)              w2T[c * 64 + t]         = f2bf(Wpre[(64 + t) * 64 + c]);
    if (t < 16)              w3T[c * 16 + t]         = f2bf(Wpre[(128 + t) * 64 + c]);
    if (t >= 64 && t < 128)  wp2T[c * 64 + (t - 64)] = f2bf(Wp2[(t - 64) * 64 + c]);
}

// ---------------- u = h@W1 + b_pre (bf16) ----------------
__global__ __launch_bounds__(256) void k_u(const float* __restrict__ h,
                                           const float* __restrict__ Wpre,
                                           const float* __restrict__ b_pre,
                                           unsigned short* __restrict__ u) {
    __shared__ float W1[64 * 64];
    __shared__ float hl[16 * 64];
    int t = threadIdx.x;
    {
        const float4* ws = (const float4*)Wpre;
        float4* wd = (float4*)W1;
        #pragma unroll
        for (int q = 0; q < 4; ++q) wd[q * 256 + t] = ws[q * 256 + t];
    }
    int base = blockIdx.x * 1024;
    ((float4*)hl)[t] = ((const float4*)(h + base))[t];
    __syncthreads();
    int r = t >> 4, f4 = (t & 15) * 4;
    float a0 = 0.f, a1 = 0.f, a2 = 0.f, a3 = 0.f;
    #pragma unroll
    for (int k = 0; k < 64; k += 4) {
        float4 hv = *(const float4*)&hl[r * 64 + k];
        #define U_STEP(KK, HK)                                     \
        {   float hk = HK;                                         \
            float4 wu = *(const float4*)&W1[(k + KK) * 64 + f4];   \
            a0 = fmaf(hk, wu.x, a0); a1 = fmaf(hk, wu.y, a1);      \
            a2 = fmaf(hk, wu.z, a2); a3 = fmaf(hk, wu.w, a3); }
        U_STEP(0, hv.x) U_STEP(1, hv.y) U_STEP(2, hv.z) U_STEP(3, hv.w)
        #undef U_STEP
    }
    float4 bp = *(const float4*)&b_pre[f4];
    us4 o;
    o.x = f2bf(a0 + bp.x); o.y = f2bf(a1 + bp.y);
    o.z = f2bf(a2 + bp.z); o.w = f2bf(a3 + bp.w);
    *(us4*)&u[base + r * 64 + f4] = o;
}

// ---------------- fused main ----------------
__global__ __launch_bounds__(256) void k_main(
    const float* __restrict__ h,
    const float* __restrict__ edge_attr,
    const int* __restrict__ nbr_idx,
    const float* __restrict__ b_post1,
    const float* __restrict__ b_post2,
    const unsigned short* __restrict__ u,       // [N][64] bf16
    const unsigned short* __restrict__ wfullT,  // [64][320] bf16
    const unsigned short* __restrict__ w2T,     // [64][64]
    const unsigned short* __restrict__ w3T,     // [64][16]
    const unsigned short* __restrict__ wp2T,    // [64][64]
    float* __restrict__ out) {
    __shared__ unsigned short u_lds[256 * 72];   // 36864 B (row stride 144B, 16B-aligned)
    __shared__ unsigned short ea_lds[256 * 24];  // 12288 B [edge][16 fe + pad8]
    __shared__ unsigned short A_lds[16 * 328];   // 10496 B [node][h(64) | agg(256) | pad8]
    __shared__ float h32[16 * 68];               // 4352 B
    __shared__ unsigned short y1_lds[16 * 72];   // 2304 B

    int t = threadIdx.x;
    int lane = t & 63;
    int w = t >> 6;             // wave id = output col-tile
    int c = lane & 15;          // frag col / A-row index
    int g = lane >> 4;          // k-group
    int col = w * 16 + c;       // global output col 0..63

    // ---- register-resident weight B-fragments (loaded once per block) ----
    s16x8 wfull[10], w2f[2], wp2f[2], w3f;
    #pragma unroll
    for (int ks = 0; ks < 10; ++ks)
        wfull[ks] = *(const s16x8*)&wfullT[col * 320 + ks * 32 + g * 8];
    #pragma unroll
    for (int ks = 0; ks < 2; ++ks) {
        w2f[ks]  = *(const s16x8*)&w2T[col * 64 + ks * 32 + g * 8];
        wp2f[ks] = *(const s16x8*)&wp2T[col * 64 + ks * 32 + g * 8];
    }
    {
        s16x8 z;
        #pragma unroll
        for (int i = 0; i < 8; ++i) z[i] = 0;
        w3f = z;
        if (g < 2) w3f = *(const s16x8*)&w3T[col * 16 + g * 8];  // k 16..31 zero-padded
    }
    float b1c = b_post1[col];
    float b2c = b_post2[col];

    for (int grp = blockIdx.x; grp < NGROUPS; grp += GRID_MAIN) {
        int node0 = grp * 16;

        // ---- stage ea: fp32 -> bf16, fully coalesced ----
        {
            const float4* src = (const float4*)(edge_attr + (size_t)node0 * 256);
            #pragma unroll
            for (int q = 0; q < 4; ++q) {
                int j = q * 256 + t;          // float4 index; edge = j>>2, chunk = j&3
                float4 x = src[j];
                us4 o;
                o.x = f2bf(x.x); o.y = f2bf(x.y); o.z = f2bf(x.z); o.w = f2bf(x.w);
                *(us4*)&ea_lds[(j >> 2) * 24 + (j & 3) * 4] = o;
            }
        }
        // ---- stage h (fp32 + bf16 copies) ----
        {
            int r = t >> 4, q = t & 15;
            float4 hv = *((const float4*)(h + (size_t)node0 * 64) + t);
            *(float4*)&h32[r * 68 + q * 4] = hv;
            us4 o;
            o.x = f2bf(hv.x); o.y = f2bf(hv.y); o.z = f2bf(hv.z); o.w = f2bf(hv.w);
            *(us4*)&A_lds[r * 328 + q * 4] = o;
        }
        // ---- stage gathered u rows (bf16, 128B/row, 8 lanes per row) ----
        {
            int row = t >> 3, seg = t & 7;
            #pragma unroll
            for (int it = 0; it < 8; ++it) {
                int e = row + 32 * it;
                int j = nbr_idx[node0 * 16 + e];
                *(s16x8*)&u_lds[e * 72 + seg * 8] =
                    *(const s16x8*)&u[(size_t)j * 64 + seg * 8];
            }
        }
        __syncthreads();

        // ---- v = h@W2 for this wave's col-tile (stays in regs) ----
        f32x4 vfrag = {0.f, 0.f, 0.f, 0.f};
        #pragma unroll
        for (int ks = 0; ks < 2; ++ks) {
            s16x8 a = *(const s16x8*)&A_lds[c * 328 + ks * 32 + g * 8];
            vfrag = __builtin_amdgcn_mfma_f32_16x16x32_bf16(a, w2f[ks], vfrag, 0, 0, 0);
        }

        // ---- pretrans + aggregation, one node (=16 edges) per MFMA ----
        #pragma unroll
        for (int nt = 0; nt < 16; ++nt) {
            float vn = __shfl(vfrag[nt & 3], ((nt >> 2) << 4) + c);
            f32x4 acc;
            #pragma unroll
            for (int i = 0; i < 4; ++i)
                acc[i] = bf2f(u_lds[(nt * 16 + g * 4 + i) * 72 + col]) + vn;
            s16x8 a;
            #pragma unroll
            for (int i = 0; i < 8; ++i) a[i] = 0;
            if (g < 2) a = *(const s16x8*)&ea_lds[(nt * 16 + c) * 24 + g * 8];
            acc = __builtin_amdgcn_mfma_f32_16x16x32_bf16(a, w3f, acc, 0, 0, 0);
            float e0 = fmaxf(acc[0], 0.f), e1 = fmaxf(acc[1], 0.f);
            float e2 = fmaxf(acc[2], 0.f), e3 = fmaxf(acc[3], 0.f);
            float s1 = (e0 + e1) + (e2 + e3);
            float s2 = fmaf(e0, e0, fmaf(e1, e1, fmaf(e2, e2, e3 * e3)));
            float mx = fmaxf(fmaxf(e0, e1), fmaxf(e2, e3));
            float mn = fminf(fminf(e0, e1), fminf(e2, e3));
            s1 += __shfl_xor(s1, 16); s2 += __shfl_xor(s2, 16);
            mx = fmaxf(mx, __shfl_xor(mx, 16)); mn = fminf(mn, __shfl_xor(mn, 16));
            s1 += __shfl_xor(s1, 32); s2 += __shfl_xor(s2, 32);
            mx = fmaxf(mx, __shfl_xor(mx, 32)); mn = fminf(mn, __shfl_xor(mn, 32));
            float mean = s1 * 0.0625f;
            float var  = fmaxf(fmaf(-mean, mean, s2 * 0.0625f), 0.f);
            float sd   = sqrtf(var + 1e-5f);
            float qv = (g == 0) ? mean : (g == 1) ? mx : (g == 2) ? mn : sd;
            A_lds[nt * 328 + 64 + g * 64 + col] = f2bf(qv);
        }
        __syncthreads();

        // ---- post1: y1 = relu([h,agg]@Wfull + b1), K=320 ----
        f32x4 y1 = {0.f, 0.f, 0.f, 0.f};
        #pragma unroll
        for (int ks = 0; ks < 10; ++ks) {
            s16x8 a = *(const s16x8*)&A_lds[c * 328 + ks * 32 + g * 8];
            y1 = __builtin_amdgcn_mfma_f32_16x16x32_bf16(a, wfull[ks], y1, 0, 0, 0);
        }
        #pragma unroll
        for (int i = 0; i < 4; ++i)
            y1_lds[(g * 4 + i) * 72 + col] = f2bf(fmaxf(y1[i] + b1c, 0.f));
        __syncthreads();

        // ---- post2 + residual ----
        f32x4 o = {0.f, 0.f, 0.f, 0.f};
        #pragma unroll
        for (int ks = 0; ks < 2; ++ks) {
            s16x8 a = *(const s16x8*)&y1_lds[c * 72 + ks * 32 + g * 8];
            o = __builtin_amdgcn_mfma_f32_16x16x32_bf16(a, wp2f[ks], o, 0, 0, 0);
        }
        #pragma unroll
        for (int i = 0; i < 4; ++i) {
            int r = g * 4 + i;
            out[(size_t)(node0 + r) * 64 + col] = o[i] + b2c + h32[r * 68 + col];
        }
        __syncthreads();   // LDS reused next group
    }
}

extern "C" void kernel_launch(void* const* d_in, const int* in_sizes, int n_in,
                              void* d_out, int out_size, void* d_ws, size_t ws_size,
                              hipStream_t stream) {
    const float* h         = (const float*)d_in[0];
    const float* edge_attr = (const float*)d_in[1];
    const int*   nbr_idx   = (const int*)d_in[2];
    const float* W_pre     = (const float*)d_in[3];
    const float* b_pre     = (const float*)d_in[4];
    const float* W_post1   = (const float*)d_in[5];
    const float* b_post1   = (const float*)d_in[6];
    const float* W_post2   = (const float*)d_in[7];
    const float* b_post2   = (const float*)d_in[8];
    float* out = (float*)d_out;

    size_t need = (size_t)N_NODES * 64 * 2 + (64 * 320 + 64 * 64 + 64 * 16 + 64 * 64) * 2;
    if (ws_size < need) return;
    unsigned short* u      = (unsigned short*)d_ws;     // [N][64] bf16
    unsigned short* wfullT = u + (size_t)N_NODES * 64;  // [64][320]
    unsigned short* w2T    = wfullT + 64 * 320;         // [64][64]
    unsigned short* w3T    = w2T + 64 * 64;             // [64][16]
    unsigned short* wp2T   = w3T + 64 * 16;             // [64][64]

    double ld = log(16.0 + 1.0);                        // log(D+1)
    const double AVG = 2.302585092994046;
    float c1 = (float)(ld / AVG);
    float c2 = (float)(AVG / ld);

    k_w<<<64, 256, 0, stream>>>(W_pre, W_post1, W_post2, wfullT, w2T, w3T, wp2T, c1, c2);
    k_u<<<N_NODES / 16, 256, 0, stream>>>(h, W_pre, b_pre, u);
    k_main<<<GRID_MAIN, 256, 0, stream>>>(h, edge_attr, nbr_idx, b_post1, b_post2,
                                          u, wfullT, w2T, w3T, wp2T, out);
}

// Round 4
// 94.767 us; speedup vs baseline: 2.1168x; 1.0266x over previous
//
#include <hip/hip_runtime.h>
#include <hip/hip_bf16.h>
#include <math.h>

// PNA layer, R4: bf16 MFMA, no u/ea LDS staging (direct-from-global operands).
//   u = h@W1 + b_pre  (bf16, precomputed)          W1 = W_pre rows 0:64
//   per 16-node group:
//     v = h@W2 (MFMA -> v_lds, wave-local)         W2 = W_pre rows 64:128
//     e = relu( mfma(ea, W3, Cinit=u[nbr]+v) )     W3 = W_pre rows 128:144
//     agg = [mean,max,min,std] over d (shfl butterfly on C-frag rows)
//     y1 = relu( [h,agg] @ Wfull + b_post1 )       Wfull = scaler-folded [320][64]
//     out = y1 @ W_post2 + b_post2 + h
// MFMA 16x16x32_bf16 layouts (m89-verified):
//   A: row = lane&15, k = (lane>>4)*8 + j
//   B: col = lane&15, k = (lane>>4)*8 + j   (weights stored transposed [col][k])
//   C/D: col = lane&15, row = (lane>>4)*4 + reg

#define N_NODES 65536
#define NGROUPS 4096
#define GRID_MAIN 1024

typedef float f32x4 __attribute__((ext_vector_type(4)));
typedef short s16x8 __attribute__((ext_vector_type(8)));
typedef unsigned short us4 __attribute__((ext_vector_type(4)));

__device__ __forceinline__ unsigned short f2bf(float f) {     // manual RNE (cold paths)
    union { float f; unsigned int u; } v; v.f = f;
    unsigned int r = v.u + 0x7fffu + ((v.u >> 16) & 1u);
    return (unsigned short)(r >> 16);
}
__device__ __forceinline__ unsigned short f2bfh(float f) {    // compiler cvt (hot paths)
    __hip_bfloat16 b = __float2bfloat16(f);
    union { __hip_bfloat16 b; unsigned short u; } v; v.b = b; return v.u;
}
__device__ __forceinline__ float bf2f(unsigned short u) {
    union { unsigned int u; float f; } v; v.u = ((unsigned int)u) << 16; return v.f;
}

// ---------------- prep: transposed bf16 weights ----------------
__global__ __launch_bounds__(256) void k_w(const float* __restrict__ Wpre,
                                           const float* __restrict__ Wp1,
                                           const float* __restrict__ Wp2,
                                           unsigned short* __restrict__ wfullT,
                                           unsigned short* __restrict__ w2T,
                                           unsigned short* __restrict__ w3T,
                                           unsigned short* __restrict__ wp2T,
                                           float c1, float c2) {
    int c = blockIdx.x;            // output col 0..63
    int t = threadIdx.x;
    for (int k = t; k < 320; k += 256) {
        float v;
        if (k < 64) v = Wp1[k * 64 + c];
        else {
            int kk = k - 64;
            v = Wp1[(64 + kk) * 64 + c] + c1 * Wp1[(320 + kk) * 64 + c]
                                        + c2 * Wp1[(576 + kk) * 64 + c];
        }
        wfullT[c * 320 + k] = f2bf(v);
    }
    if (t < 64)              w2T[c * 64 + t]         = f2bf(Wpre[(64 + t) * 64 + c]);
    if (t < 16)              w3T[c * 16 + t]         = f2bf(Wpre[(128 + t) * 64 + c]);
    if (t >= 64 && t < 128)  wp2T[c * 64 + (t - 64)] = f2bf(Wp2[(t - 64) * 64 + c]);
}

// ---------------- u = h@W1 + b_pre (bf16) ----------------
__global__ __launch_bounds__(256) void k_u(const float* __restrict__ h,
                                           const float* __restrict__ Wpre,
                                           const float* __restrict__ b_pre,
                                           unsigned short* __restrict__ u) {
    __shared__ float W1[64 * 64];
    __shared__ float hl[16 * 64];
    int t = threadIdx.x;
    {
        const float4* ws = (const float4*)Wpre;
        float4* wd = (float4*)W1;
        #pragma unroll
        for (int q = 0; q < 4; ++q) wd[q * 256 + t] = ws[q * 256 + t];
    }
    int base = blockIdx.x * 1024;
    ((float4*)hl)[t] = ((const float4*)(h + base))[t];
    __syncthreads();
    int r = t >> 4, f4 = (t & 15) * 4;
    float a0 = 0.f, a1 = 0.f, a2 = 0.f, a3 = 0.f;
    #pragma unroll
    for (int k = 0; k < 64; k += 4) {
        float4 hv = *(const float4*)&hl[r * 64 + k];
        #define U_STEP(KK, HK)                                     \
        {   float hk = HK;                                         \
            float4 wu = *(const float4*)&W1[(k + KK) * 64 + f4];   \
            a0 = fmaf(hk, wu.x, a0); a1 = fmaf(hk, wu.y, a1);      \
            a2 = fmaf(hk, wu.z, a2); a3 = fmaf(hk, wu.w, a3); }
        U_STEP(0, hv.x) U_STEP(1, hv.y) U_STEP(2, hv.z) U_STEP(3, hv.w)
        #undef U_STEP
    }
    float4 bp = *(const float4*)&b_pre[f4];
    us4 o;
    o.x = f2bf(a0 + bp.x); o.y = f2bf(a1 + bp.y);
    o.z = f2bf(a2 + bp.z); o.w = f2bf(a3 + bp.w);
    *(us4*)&u[base + r * 64 + f4] = o;
}

// ---------------- fused main ----------------
__global__ __launch_bounds__(256, 3) void k_main(
    const float* __restrict__ h,
    const float* __restrict__ edge_attr,
    const int* __restrict__ nbr_idx,
    const float* __restrict__ b_post1,
    const float* __restrict__ b_post2,
    const unsigned short* __restrict__ u,       // [N][64] bf16
    const unsigned short* __restrict__ wfullT,  // [64][320] bf16
    const unsigned short* __restrict__ w2T,     // [64][64]
    const unsigned short* __restrict__ w3T,     // [64][16]
    const unsigned short* __restrict__ wp2T,    // [64][64]
    float* __restrict__ out) {
    __shared__ unsigned short A_lds[16 * 344];   // 11008 B  [node][h(64)|agg(256)|pad]
    __shared__ float h32[16 * 68];               // 4352 B
    __shared__ float v_lds[16 * 68];             // 4352 B   (wave-local RW, no barrier)
    __shared__ unsigned short y1_lds[16 * 72];   // 2304 B
    __shared__ int nbl[256];                     // 1024 B
    // total ~23 KB -> LDS allows 6 blocks/CU; VGPR cap 170 -> 3 blocks/CU

    int t = threadIdx.x;
    int lane = t & 63;
    int w = t >> 6;             // wave id = output col-tile
    int c = lane & 15;          // frag col / A-row index
    int g = lane >> 4;          // k-group
    int col = w * 16 + c;       // global output col 0..63

    // ---- register-resident weight B-fragments (loaded once per block) ----
    s16x8 wfull[10], w2f[2], wp2f[2], w3f;
    #pragma unroll
    for (int ks = 0; ks < 10; ++ks)
        wfull[ks] = *(const s16x8*)&wfullT[col * 320 + ks * 32 + g * 8];
    #pragma unroll
    for (int ks = 0; ks < 2; ++ks) {
        w2f[ks]  = *(const s16x8*)&w2T[col * 64 + ks * 32 + g * 8];
        wp2f[ks] = *(const s16x8*)&wp2T[col * 64 + ks * 32 + g * 8];
    }
    {
        s16x8 z;
        #pragma unroll
        for (int i = 0; i < 8; ++i) z[i] = 0;
        w3f = z;
        if (g < 2) w3f = *(const s16x8*)&w3T[col * 16 + g * 8];  // k 16..31 zero-padded
    }
    float b1c = b_post1[col];
    float b2c = b_post2[col];

    for (int grp = blockIdx.x; grp < NGROUPS; grp += GRID_MAIN) {
        int node0 = grp * 16;

        // ---- stage h (fp32 + bf16 into A_lds) + neighbor indices ----
        {
            int r = t >> 4, q = t & 15;
            float4 hv = *((const float4*)(h + (size_t)node0 * 64) + t);
            *(float4*)&h32[r * 68 + q * 4] = hv;
            us4 o;
            o.x = f2bfh(hv.x); o.y = f2bfh(hv.y); o.z = f2bfh(hv.z); o.w = f2bfh(hv.w);
            *(us4*)&A_lds[r * 344 + q * 4] = o;
            nbl[t] = nbr_idx[node0 * 16 + t];
        }
        __syncthreads();

        // ---- v = h@W2 for this wave's col-tile -> v_lds (same-wave RW, no barrier) ----
        {
            f32x4 vfrag = {0.f, 0.f, 0.f, 0.f};
            #pragma unroll
            for (int ks = 0; ks < 2; ++ks) {
                s16x8 a = *(const s16x8*)&A_lds[c * 344 + ks * 32 + g * 8];
                vfrag = __builtin_amdgcn_mfma_f32_16x16x32_bf16(a, w2f[ks], vfrag, 0, 0, 0);
            }
            #pragma unroll
            for (int i = 0; i < 4; ++i)
                v_lds[(g * 4 + i) * 68 + col] = vfrag[i];
        }

        // ---- pretrans + aggregation, one node (=16 edges) per MFMA ----
        #pragma unroll
        for (int nt = 0; nt < 16; ++nt) {
            float vn = v_lds[nt * 68 + col];
            // C-init: gathered u + v (per-lane global ushort loads, L2/L3-served)
            f32x4 acc;
            #pragma unroll
            for (int i = 0; i < 4; ++i) {
                int j = nbl[nt * 16 + g * 4 + i];
                acc[i] = bf2f(u[(size_t)j * 64 + col]) + vn;
            }
            // A-frag: edge_attr straight from global (g<2 lanes; k 16..31 zero)
            s16x8 a;
            #pragma unroll
            for (int i = 0; i < 8; ++i) a[i] = 0;
            if (g < 2) {
                const float* p = edge_attr + (size_t)(node0 + nt) * 256 + c * 16 + g * 8;
                float4 x0 = *(const float4*)p;
                float4 x1 = *(const float4*)(p + 4);
                a[0] = (short)f2bfh(x0.x); a[1] = (short)f2bfh(x0.y);
                a[2] = (short)f2bfh(x0.z); a[3] = (short)f2bfh(x0.w);
                a[4] = (short)f2bfh(x1.x); a[5] = (short)f2bfh(x1.y);
                a[6] = (short)f2bfh(x1.z); a[7] = (short)f2bfh(x1.w);
            }
            acc = __builtin_amdgcn_mfma_f32_16x16x32_bf16(a, w3f, acc, 0, 0, 0);
            // rows of acc = neighbor d = g*4+i ; reduce over d (in-reg + xor16 + xor32)
            float e0 = fmaxf(acc[0], 0.f), e1 = fmaxf(acc[1], 0.f);
            float e2 = fmaxf(acc[2], 0.f), e3 = fmaxf(acc[3], 0.f);
            float s1 = (e0 + e1) + (e2 + e3);
            float s2 = fmaf(e0, e0, fmaf(e1, e1, fmaf(e2, e2, e3 * e3)));
            float mx = fmaxf(fmaxf(e0, e1), fmaxf(e2, e3));
            float mn = fminf(fminf(e0, e1), fminf(e2, e3));
            s1 += __shfl_xor(s1, 16); s2 += __shfl_xor(s2, 16);
            mx = fmaxf(mx, __shfl_xor(mx, 16)); mn = fminf(mn, __shfl_xor(mn, 16));
            s1 += __shfl_xor(s1, 32); s2 += __shfl_xor(s2, 32);
            mx = fmaxf(mx, __shfl_xor(mx, 32)); mn = fminf(mn, __shfl_xor(mn, 32));
            float mean = s1 * 0.0625f;
            float var  = fmaxf(fmaf(-mean, mean, s2 * 0.0625f), 0.f);
            float sd   = sqrtf(var + 1e-5f);
            float qv = (g == 0) ? mean : (g == 1) ? mx : (g == 2) ? mn : sd;
            A_lds[nt * 344 + 64 + g * 64 + col] = f2bf(qv);
        }
        __syncthreads();

        // ---- post1: y1 = relu([h,agg]@Wfull + b1), K=320 ----
        {
            f32x4 y1 = {0.f, 0.f, 0.f, 0.f};
            #pragma unroll
            for (int ks = 0; ks < 10; ++ks) {
                s16x8 a = *(const s16x8*)&A_lds[c * 344 + ks * 32 + g * 8];
                y1 = __builtin_amdgcn_mfma_f32_16x16x32_bf16(a, wfull[ks], y1, 0, 0, 0);
            }
            #pragma unroll
            for (int i = 0; i < 4; ++i)
                y1_lds[(g * 4 + i) * 72 + col] = f2bf(fmaxf(y1[i] + b1c, 0.f));
        }
        __syncthreads();

        // ---- post2 + residual ----
        {
            f32x4 o = {0.f, 0.f, 0.f, 0.f};
            #pragma unroll
            for (int ks = 0; ks < 2; ++ks) {
                s16x8 a = *(const s16x8*)&y1_lds[c * 72 + ks * 32 + g * 8];
                o = __builtin_amdgcn_mfma_f32_16x16x32_bf16(a, wp2f[ks], o, 0, 0, 0);
            }
            #pragma unroll
            for (int i = 0; i < 4; ++i) {
                int r = g * 4 + i;
                out[(size_t)(node0 + r) * 64 + col] = o[i] + b2c + h32[r * 68 + col];
            }
        }
        __syncthreads();   // LDS reused next group
    }
}

extern "C" void kernel_launch(void* const* d_in, const int* in_sizes, int n_in,
                              void* d_out, int out_size, void* d_ws, size_t ws_size,
                              hipStream_t stream) {
    const float* h         = (const float*)d_in[0];
    const float* edge_attr = (const float*)d_in[1];
    const int*   nbr_idx   = (const int*)d_in[2];
    const float* W_pre     = (const float*)d_in[3];
    const float* b_pre     = (const float*)d_in[4];
    const float* W_post1   = (const float*)d_in[5];
    const float* b_post1   = (const float*)d_in[6];
    const float* W_post2   = (const float*)d_in[7];
    const float* b_post2   = (const float*)d_in[8];
    float* out = (float*)d_out;

    size_t need = (size_t)N_NODES * 64 * 2 + (64 * 320 + 64 * 64 + 64 * 16 + 64 * 64) * 2;
    if (ws_size < need) return;
    unsigned short* u      = (unsigned short*)d_ws;     // [N][64] bf16
    unsigned short* wfullT = u + (size_t)N_NODES * 64;  // [64][320]
    unsigned short* w2T    = wfullT + 64 * 320;         // [64][64]
    unsigned short* w3T    = w2T + 64 * 64;             // [64][16]
    unsigned short* wp2T   = w3T + 64 * 16;             // [64][64]

    double ld = log(16.0 + 1.0);                        // log(D+1)
    const double AVG = 2.302585092994046;
    float c1 = (float)(ld / AVG);
    float c2 = (float)(AVG / ld);

    k_w<<<64, 256, 0, stream>>>(W_pre, W_post1, W_post2, wfullT, w2T, w3T, wp2T, c1, c2);
    k_u<<<N_NODES / 16, 256, 0, stream>>>(h, W_pre, b_pre, u);
    k_main<<<GRID_MAIN, 256, 0, stream>>>(h, edge_attr, nbr_idx, b_post1, b_post2,
                                          u, wfullT, w2T, w3T, wp2T, out);
}